// Round 6
// baseline (482.493 us; speedup 1.0000x reference)
//
#include <hip/hip_runtime.h>
#include <hip/hip_fp16.h>

#define NT 25
#define NXY 448
#define NPIX (448*448)
#define PXY 115
#define SXY 111

#define TW 32
#define TH 8
#define CH 5          // output frames per time-chunk
#define NZ 5          // number of time chunks (NT/CH)
#define GSL 8         // gram spatial slices

// complex MAC, all-fp16 packed (full-rate v_pk_fma_f16, 2 cyc/instr):
// z=(zr,zi), x=(xr,xi), w=(wr,wi)  (each one VGPR/SGPR holding 2xfp16)
//  pk1: (zr,zi) += (xr,xr)*(wr,wi)
//  pk2: (zr,zi) += (xi,xi)*(-wi,wr)
// weight is wave-uniform -> SGPR source (legal: 1 sgpr read per VOP3P instr)
#define CMACH(z, x, w)                                                                             \
    asm("v_pk_fma_f16 %0, %1, %2, %0 op_sel:[0,0,0] op_sel_hi:[0,1,1]"                             \
        : "+v"(z) : "v"(x), "s"(w));                                                               \
    asm("v_pk_fma_f16 %0, %1, %2, %0 op_sel:[1,1,0] op_sel_hi:[1,0,1] neg_lo:[0,1,0]"              \
        : "+v"(z) : "v"(x), "s"(w));

#define PKRELU(d, a)                                                                               \
    asm("v_pk_max_f16 %0, %1, 0" : "=v"(d) : "v"(a))

static __device__ __forceinline__ unsigned int packh2f(float lo, float hi) {
    auto h = __builtin_amdgcn_cvt_pkrtz(lo, hi);   // v_cvt_pkrtz_f16_f32
    return __builtin_bit_cast(unsigned int, h);
}

// ---------------- K0: pack weights into fp16 (wr,wi) layout
// wt1h[tap*12 + c]        = pack(w1r,w1i)  for w1[c*25+tap]
// wt2h[(c1*3+dt)*12 + c2] = pack(w2r,w2i)  for w2[(c2*12+c1)*3+dt]
__global__ void k_prep(const float* __restrict__ w1r, const float* __restrict__ w1i,
                       const float* __restrict__ w2r, const float* __restrict__ w2i,
                       unsigned int* __restrict__ wt1h, unsigned int* __restrict__ wt2h)
{
    int i = blockIdx.x * 256 + threadIdx.x;
    auto pk = [](float a, float b) {
        unsigned short ua = __half_as_ushort(__float2half_rn(a));
        unsigned short ub = __half_as_ushort(__float2half_rn(b));
        return (unsigned int)ua | ((unsigned int)ub << 16);
    };
    if (i < 300) {
        int c = i / 25, tap = i - c * 25;
        wt1h[tap*12 + c] = pk(w1r[i], w1i[i]);
    }
    if (i < 432) {
        int dt = i % 3; int t = i / 3; int c1 = t % 12; int c2 = t / 12;
        wt2h[(c1*3+dt)*12 + c2] = pk(w2r[i], w2i[i]);
    }
}

// ---------------- K1 (merged): z<NZ -> fused conv pipeline; z==NZ -> gram partials.
// Conv: conv1(1->12,5x5)+ReLU -> conv2(12->12,3t)+ReLU -> conv3(12->1) real
//       out = (x_re - dR*tsc)*pwv.  All MACs are v_pk_fma_f16 with SGPR weights,
//       packed-fp16 accumulators (error << tsc*pwv scale).
__global__ __launch_bounds__(256, 8) void k_work(
    const float* __restrict__ re, const float* __restrict__ im,
    const unsigned int* __restrict__ wt1h, const unsigned int* __restrict__ wt2h,
    const float* __restrict__ b1r, const float* __restrict__ b1i,
    const float* __restrict__ b2r, const float* __restrict__ b2i,
    const float* __restrict__ w3r, const float* __restrict__ w3i,
    const float* __restrict__ b3r,
    const float* __restrict__ tau_w, const float* __restrict__ p_w,
    const int* __restrict__ num_iter,
    float* __restrict__ out, float* __restrict__ gP)
{
    __shared__ unsigned int s_inv[2][12*36];   // double-buffered fp16 (re,im) input tile
    __shared__ float s_red[4][50];             // gram path only

    const int tid = threadIdx.x;

    if (blockIdx.z == NZ) {
        // ---------------- gram path ----------------
        const int gid = blockIdx.x + 14 * blockIdx.y;
        if (gid >= 80 * GSL) return;
        const int b = gid >> 3;              // 0..79 = chunk*16 + i*4 + j
        const int slice = gid & 7;
        const int chunk = b >> 4;
        const int pidx = b & 15;
        const int X0 = (pidx >> 2) * SXY;
        const int Y0 = (pidx & 3) * SXY;

        float acc[50];
        #pragma unroll
        for (int k = 0; k < 50; ++k) acc[k] = 0.f;

        const int npx = PXY * PXY;           // 13225
        for (int pi = slice*256 + tid; pi < npx; pi += 256*GSL) {
            int px = pi / PXY, py = pi % PXY;
            size_t base = (size_t)(X0 + px) * NXY + (Y0 + py);
            float xr[5], xi[5];
            #pragma unroll
            for (int r = 0; r < 5; ++r) {
                size_t a = (size_t)(chunk*5 + r) * NPIX + base;
                xr[r] = re[a]; xi[r] = im[a];
            }
            #pragma unroll
            for (int t1 = 0; t1 < 5; ++t1)
                #pragma unroll
                for (int t2 = 0; t2 < 5; ++t2) {
                    acc[(t1*5+t2)*2]   += xr[t1]*xr[t2] + xi[t1]*xi[t2];
                    acc[(t1*5+t2)*2+1] += xi[t1]*xr[t2] - xr[t1]*xi[t2];
                }
        }
        #pragma unroll
        for (int k = 0; k < 50; ++k) {
            float v = acc[k];
            for (int m = 32; m > 0; m >>= 1) v += __shfl_xor(v, m, 64);
            acc[k] = v;
        }
        int lane = tid & 63, wid = tid >> 6;
        if (lane == 0) {
            #pragma unroll
            for (int k = 0; k < 50; ++k) s_red[wid][k] = acc[k];
        }
        __syncthreads();
        if (tid < 50) {
            gP[(b*GSL + slice)*50 + tid] =
                s_red[0][tid] + s_red[1][tid] + s_red[2][tid] + s_red[3][tid];
        }
        return;
    }

    // ---------------- conv path ----------------
    const int tx = tid & 31;
    const int ty = tid >> 5;
    const int Y0 = blockIdx.x * TW;
    const int X0 = blockIdx.y * TH;
    const int z  = blockIdx.z;            // time chunk
    const int z0 = z * CH;                // first output frame of this chunk
    const int fs = (z == 0) ? 0 : z0 - 1; // first conv1 frame
    const int fe = (z0 + CH < NT) ? z0 + CH : NT - 1;  // last conv1 frame

    // wave-uniform params
    float rw3[12], iw3[12];
    unsigned int ub1[12], ub2[12];        // packed fp16 biases
    #pragma unroll
    for (int c = 0; c < 12; ++c) {
        ub1[c] = packh2f(b1r[c], b1i[c]);
        ub2[c] = packh2f(b2r[c], b2i[c]);
        rw3[c] = w3r[c]; iw3[c] = w3i[c];
    }
    const float b3v = b3r[0];
    const float tsc = fmaxf(tau_w[0], 0.f) / (float)num_iter[0];
    const float pwv = fmaxf(p_w[0], 0.f);

    // staging geometry (frame-independent): item0 = tid, item1 = tid+256 (if < 432)
    const int idx1 = tid + 256;
    int r0 = tid / 36, c0 = tid - r0*36;
    int gx0 = X0 + r0 - 2, gy0 = Y0 + c0 - 2;
    bool k0 = (gx0 >= 0) && (gx0 < NXY) && (gy0 >= 0) && (gy0 < NXY);
    const int a0 = (k0 ? gx0 : 0) * NXY + (k0 ? gy0 : 0);
    const float m0 = k0 ? 1.f : 0.f;
    int r1 = idx1 / 36, c1_ = idx1 - r1*36;
    int gx1 = X0 + r1 - 2, gy1 = Y0 + c1_ - 2;
    bool k1 = (gx1 >= 0) && (gx1 < NXY) && (gy1 >= 0) && (gy1 < NXY);
    const int a1 = (k1 ? gx1 : 0) * NXY + (k1 ? gy1 : 0);
    const float m1 = k1 ? 1.f : 0.f;

    // persistent h1 slots (relu'd fp16 pairs): hA=h[t-1], hB=h[t], hC=h[t+1]
    unsigned int hA[12], hB[12], hC[12];
    #pragma unroll
    for (int c = 0; c < 12; ++c) { hA[c] = 0u; hB[c] = 0u; hC[c] = 0u; }

    // conv1 for frame tf -> relu (packed) -> hs
    auto conv1_to = [&](int tf, unsigned int (&hs)[12]) {
        unsigned int a[12];
        #pragma unroll
        for (int c = 0; c < 12; ++c) a[c] = ub1[c];
        const unsigned int* sin_ = s_inv[tf & 1];
        #pragma unroll 1
        for (int ky = 0; ky < 5; ++ky) {
            const unsigned int* irow = &sin_[(ty+ky)*36 + tx];
            const unsigned int* wrow = &wt1h[ky*5*12];
            #pragma unroll
            for (int kx = 0; kx < 5; ++kx) {
                unsigned int x = irow[kx];
                const unsigned int* wp = wrow + kx*12;
                #pragma unroll
                for (int c = 0; c < 12; ++c) {
                    unsigned int w = wp[c];
                    CMACH(a[c], x, w);
                }
            }
        }
        #pragma unroll
        for (int c = 0; c < 12; ++c) { PKRELU(hs[c], a[c]); }
    };

    // conv2(+ReLU)+conv3+epilogue for output frame tc
    auto do_out = [&](int tc, unsigned int (&hp)[12], unsigned int (&hc)[12],
                      unsigned int (&hn)[12], bool hasP, bool hasN) {
        size_t idx = (size_t)tc*NPIX + (size_t)(X0+ty)*NXY + (Y0+tx);
        float reval = re[idx];             // issue early, hides under MACs
        unsigned int zz[12];
        #pragma unroll
        for (int c = 0; c < 12; ++c) zz[c] = ub2[c];
        if (hasP) {
            #pragma unroll
            for (int c1 = 0; c1 < 12; ++c1) {
                unsigned int x = hp[c1];
                const unsigned int* wp = &wt2h[(c1*3+0)*12];
                #pragma unroll
                for (int c2 = 0; c2 < 12; ++c2) {
                    unsigned int w = wp[c2];
                    CMACH(zz[c2], x, w);
                }
            }
        }
        {
            #pragma unroll
            for (int c1 = 0; c1 < 12; ++c1) {
                unsigned int x = hc[c1];
                const unsigned int* wp = &wt2h[(c1*3+1)*12];
                #pragma unroll
                for (int c2 = 0; c2 < 12; ++c2) {
                    unsigned int w = wp[c2];
                    CMACH(zz[c2], x, w);
                }
            }
        }
        if (hasN) {
            #pragma unroll
            for (int c1 = 0; c1 < 12; ++c1) {
                unsigned int x = hn[c1];
                const unsigned int* wp = &wt2h[(c1*3+2)*12];
                #pragma unroll
                for (int c2 = 0; c2 < 12; ++c2) {
                    unsigned int w = wp[c2];
                    CMACH(zz[c2], x, w);
                }
            }
        }
        float dR = b3v;
        #pragma unroll
        for (int c = 0; c < 12; ++c) {
            unsigned int zr;
            PKRELU(zr, zz[c]);
            __half2 hz = __builtin_bit_cast(__half2, zr);
            dR += __low2float(hz)*rw3[c] - __high2float(hz)*iw3[c];
        }
        out[idx] = (reval - dR * tsc) * pwv;
    };

    // prologue: stage frame fs
    {
        const float* rp = re + (size_t)fs * NPIX;
        const float* ip = im + (size_t)fs * NPIX;
        float pr0 = rp[a0], pi0 = ip[a0];
        float pr1 = 0.f, pi1 = 0.f;
        if (idx1 < 432) { pr1 = rp[a1]; pi1 = ip[a1]; }
        unsigned int* dst = s_inv[fs & 1];
        dst[tid] = packh2f(pr0*m0, pi0*m0);
        if (idx1 < 432) dst[idx1] = packh2f(pr1*m1, pi1*m1);
    }
    __syncthreads();

    #pragma unroll 1
    for (int f = fs; f <= fe; ++f) {
        // (1) issue next frame's loads early -> regs (latency hides under compute)
        float pr0 = 0.f, pi0 = 0.f, pr1 = 0.f, pi1 = 0.f;
        const bool more = (f < fe);
        if (more) {
            const float* rp = re + (size_t)(f+1) * NPIX;
            const float* ip = im + (size_t)(f+1) * NPIX;
            pr0 = rp[a0]; pi0 = ip[a0];
            if (idx1 < 432) { pr1 = rp[a1]; pi1 = ip[a1]; }
        }
        // (2) compute on already-staged frame f
        conv1_to(f, hC);
        const int tc = f - 1;
        if (f > fs && tc >= z0)
            do_out(tc, hA, hB, hC, tc >= 1, true);
        // (3) write prefetched regs to the other LDS buffer, then one barrier
        if (more) {
            unsigned int* dst = s_inv[(f+1) & 1];
            dst[tid] = packh2f(pr0*m0, pi0*m0);
            if (idx1 < 432) dst[idx1] = packh2f(pr1*m1, pi1*m1);
        }
        __syncthreads();
        #pragma unroll
        for (int c = 0; c < 12; ++c) { hA[c] = hB[c]; hB[c] = hC[c]; }
    }
    // final frame of the last chunk: tc = 24
    if (fe == NT - 1)
        do_out(NT - 1, hA, hB, hC, true, false);
}

// ---------------- K2: fold Gram partials -> Jacobi eig -> W (LDS) -> region-avg gA
__global__ __launch_bounds__(128) void k_post(
    const float* __restrict__ gP, const float* __restrict__ thres,
    float* __restrict__ gA)
{
    __shared__ float sW[80*50];
    const int tid = threadIdx.x;
    if (tid < 80) {
        const int b = tid;
        float Ar[5][5], Ai[5][5], Vr[5][5], Vi[5][5];
        #pragma unroll
        for (int a = 0; a < 5; ++a)
            #pragma unroll
            for (int c = 0; c < 5; ++c) {
                float sr = 0.f, si = 0.f;
                #pragma unroll
                for (int sl = 0; sl < GSL; ++sl) {
                    sr += gP[(b*GSL + sl)*50 + (a*5+c)*2];
                    si += gP[(b*GSL + sl)*50 + (a*5+c)*2 + 1];
                }
                Ar[a][c] = sr; Ai[a][c] = si;
                Vr[a][c] = (a==c) ? 1.f : 0.f;
                Vi[a][c] = 0.f;
            }
        for (int sw = 0; sw < 9; ++sw) {
            #pragma unroll
            for (int p = 0; p < 4; ++p) {
                #pragma unroll
                for (int q = p+1; q < 5; ++q) {
                    float apr = Ar[p][q], api = Ai[p][q];
                    float n2 = apr*apr + api*api;
                    if (n2 > 1e-24f) {
                        float mlen = sqrtf(n2);
                        float phr = apr / mlen, phi = api / mlen;
                        float tau = (Ar[q][q] - Ar[p][p]) / (2.f * mlen);
                        float tt = (tau >= 0.f ? 1.f : -1.f) / (fabsf(tau) + sqrtf(1.f + tau*tau));
                        float cc = 1.f / sqrtf(1.f + tt*tt);
                        float ss = tt * cc;
                        float wr2 = ss * phr, wi2 = ss * phi;
                        #pragma unroll
                        for (int k = 0; k < 5; ++k) {
                            float xr = Ar[k][p], xi2 = Ai[k][p];
                            float yr = Ar[k][q], yi = Ai[k][q];
                            Ar[k][p] = cc*xr - (wr2*yr + wi2*yi);
                            Ai[k][p] = cc*xi2 - (wr2*yi - wi2*yr);
                            Ar[k][q] = wr2*xr - wi2*xi2 + cc*yr;
                            Ai[k][q] = wr2*xi2 + wi2*xr + cc*yi;
                            float vxr = Vr[k][p], vxi = Vi[k][p];
                            float vyr = Vr[k][q], vyi = Vi[k][q];
                            Vr[k][p] = cc*vxr - (wr2*vyr + wi2*vyi);
                            Vi[k][p] = cc*vxi - (wr2*vyi - wi2*vyr);
                            Vr[k][q] = wr2*vxr - wi2*vxi + cc*vyr;
                            Vi[k][q] = wr2*vxi + wi2*vxr + cc*vyi;
                        }
                        #pragma unroll
                        for (int k = 0; k < 5; ++k) {
                            float xr = Ar[p][k], xi2 = Ai[p][k];
                            float yr = Ar[q][k], yi = Ai[q][k];
                            Ar[p][k] = cc*xr - (wr2*yr - wi2*yi);
                            Ai[p][k] = cc*xi2 - (wr2*yi + wi2*yr);
                            Ar[q][k] = wr2*xr + wi2*xi2 + cc*yr;
                            Ai[q][k] = wr2*xi2 - wi2*xr + cc*yi;
                        }
                    }
                }
            }
        }
        float sv[5], s0 = 0.f;
        #pragma unroll
        for (int k = 0; k < 5; ++k) { sv[k] = sqrtf(fmaxf(Ar[k][k], 0.f)); s0 = fmaxf(s0, sv[k]); }
        float th = fmaxf(thres[b], 0.f) * s0;
        float ratio[5];
        #pragma unroll
        for (int k = 0; k < 5; ++k)
            ratio[k] = sv[k] > 0.f ? fmaxf(sv[k] - th, 0.f) / sv[k] : 0.f;
        #pragma unroll
        for (int a = 0; a < 5; ++a)
            #pragma unroll
            for (int c = 0; c < 5; ++c) {
                float wr = 0.f, wi = 0.f;
                #pragma unroll
                for (int k = 0; k < 5; ++k) {
                    wr += ratio[k] * (Vr[a][k]*Vr[c][k] + Vi[a][k]*Vi[c][k]);
                    wi += ratio[k] * (Vi[a][k]*Vr[c][k] - Vr[a][k]*Vi[c][k]);
                }
                sW[b*50 + (a*5+c)*2]   = wr;
                sW[b*50 + (a*5+c)*2+1] = wi;
            }
    }
    __syncthreads();
    for (int it = tid; it < 245*25; it += 128) {
        int blk = it / 25, e = it % 25;
        int chunk = blk / 49;
        int rem = blk % 49;
        int rx = rem / 7, ry = rem % 7;
        int i0 = rx >> 1, i1 = (rx + 1) >> 1;
        int j0 = ry >> 1, j1 = (ry + 1) >> 1;
        float sr = 0.f, si = 0.f; int cnt = 0;
        for (int i = i0; i <= i1; ++i)
            for (int j = j0; j <= j1; ++j) {
                int b = chunk*16 + i*4 + j;
                sr += sW[b*50 + e*2];
                si += sW[b*50 + e*2 + 1];
                ++cnt;
            }
        float inv = 1.f / (float)cnt;
        gA[blk*50 + e*2]   = sr * inv;
        gA[blk*50 + e*2+1] = si * inv;
    }
}

// ---------------- K4: q_re = Re(Wavg * x5) ; out += q_re*(1-p_w)   (fp32 RMW)
__global__ __launch_bounds__(256) void k_final(
    const float* __restrict__ re, const float* __restrict__ im,
    const float* __restrict__ gA, const float* __restrict__ p_w,
    float* __restrict__ out)
{
    int pix = blockIdx.x * 256 + threadIdx.x;
    int chunk = blockIdx.y;
    int X = pix / NXY, Y = pix % NXY;
    int i_lo = (X - 4) / SXY; if (i_lo < 0) i_lo = 0;
    int i_hi = X / SXY;       if (i_hi > 3) i_hi = 3;
    int j_lo = (Y - 4) / SXY; if (j_lo < 0) j_lo = 0;
    int j_hi = Y / SXY;       if (j_hi > 3) j_hi = 3;
    int rx = i_lo + i_hi, ry = j_lo + j_hi;
    const float* wa = gA + (size_t)(chunk*49 + rx*7 + ry) * 50;
    float Wr[5][5], Wi[5][5];
    #pragma unroll
    for (int a = 0; a < 5; ++a)
        #pragma unroll
        for (int r = 0; r < 5; ++r) {
            Wr[a][r] = wa[(a*5+r)*2];
            Wi[a][r] = wa[(a*5+r)*2+1];
        }
    float xr[5], xi[5];
    #pragma unroll
    for (int r = 0; r < 5; ++r) {
        size_t a = (size_t)(chunk*5+r)*NPIX + pix;
        xr[r] = re[a]; xi[r] = im[a];
    }
    float qwv = 1.f - p_w[0];
    #pragma unroll
    for (int tl = 0; tl < 5; ++tl) {
        float qr = 0.f;
        #pragma unroll
        for (int r = 0; r < 5; ++r)
            qr += Wr[tl][r]*xr[r] - Wi[tl][r]*xi[r];
        size_t idx = (size_t)(chunk*5+tl)*NPIX + pix;
        out[idx] += qr*qwv;
    }
}

extern "C" void kernel_launch(void* const* d_in, const int* in_sizes, int n_in,
                              void* d_out, int out_size, void* d_ws, size_t ws_size,
                              hipStream_t stream)
{
    const float* re    = (const float*)d_in[0];
    const float* im    = (const float*)d_in[1];
    const float* w1r   = (const float*)d_in[2];
    const float* w1i   = (const float*)d_in[3];
    const float* b1r   = (const float*)d_in[4];
    const float* b1i   = (const float*)d_in[5];
    const float* w2r   = (const float*)d_in[6];
    const float* w2i   = (const float*)d_in[7];
    const float* b2r   = (const float*)d_in[8];
    const float* b2i   = (const float*)d_in[9];
    const float* w3r   = (const float*)d_in[10];
    const float* w3i   = (const float*)d_in[11];
    const float* b3r   = (const float*)d_in[12];
    const float* thres = (const float*)d_in[14];
    const float* tau_w = (const float*)d_in[15];
    const float* p_w   = (const float*)d_in[16];
    const int* num_iter= (const int*)d_in[17];

    float* ws = (float*)d_ws;
    unsigned int* wt1h = (unsigned int*)ws;          // 300 uints
    unsigned int* wt2h = wt1h + 512;                 // 432 uints (padded)
    float* gP  = (float*)(wt2h + 512);               // 80*GSL*50 = 32000 floats
    float* gA  = gP + 80*GSL*50;                     // 245*50 floats

    float* outf = (float*)d_out;

    k_prep<<<2, 256, 0, stream>>>(w1r, w1i, w2r, w2i, wt1h, wt2h);
    dim3 g1(NXY/TW, NXY/TH, NZ + 1);                 // z==NZ slice = gram blocks
    k_work<<<g1, 256, 0, stream>>>(re, im, wt1h, wt2h,
                                   b1r, b1i, b2r, b2i, w3r, w3i, b3r,
                                   tau_w, p_w, num_iter, outf, gP);
    k_post<<<1, 128, 0, stream>>>(gP, thres, gA);
    dim3 g4(NPIX/256, 5);
    k_final<<<g4, 256, 0, stream>>>(re, im, gA, p_w, outf);
}

// Round 7
// 455.952 us; speedup vs baseline: 1.0582x; 1.0582x over previous
//
#include <hip/hip_runtime.h>
#include <hip/hip_fp16.h>

#define NT 25
#define NXY 448
#define NPIX (448*448)
#define PXY 115
#define SXY 111

#define TW 32
#define TH 8
#define CH 5          // output frames per time-chunk
#define NZ 5          // number of time chunks (NT/CH)
#define GSL 8         // gram spatial slices

// complex MAC, all-fp16 packed (v_pk_fma_f16):
// z=(zr,zi), x=(xr,xi), w=(wr,wi)  (each one VGPR/SGPR holding 2xfp16)
//  pk1: (zr,zi) += (xr,xr)*(wr,wi)
//  pk2: (zr,zi) += (xi,xi)*(-wi,wr)
// weight is wave-uniform -> SGPR source (legal: 1 sgpr read per VOP3P instr)
#define CMACH(z, x, w)                                                                             \
    asm("v_pk_fma_f16 %0, %1, %2, %0 op_sel:[0,0,0] op_sel_hi:[0,1,1]"                             \
        : "+v"(z) : "v"(x), "s"(w));                                                               \
    asm("v_pk_fma_f16 %0, %1, %2, %0 op_sel:[1,1,0] op_sel_hi:[1,0,1] neg_lo:[0,1,0]"              \
        : "+v"(z) : "v"(x), "s"(w));

#define PKRELU(d, a)                                                                               \
    asm("v_pk_max_f16 %0, %1, 0" : "=v"(d) : "v"(a))

static __device__ __forceinline__ unsigned int packh2f(float lo, float hi) {
    auto h = __builtin_amdgcn_cvt_pkrtz(lo, hi);   // v_cvt_pkrtz_f16_f32
    return __builtin_bit_cast(unsigned int, h);
}

// ---------------- K0: pack weights into fp16 (wr,wi) layout
// wt1h[tap*12 + c]        = pack(w1r,w1i)  for w1[c*25+tap]
// wt2h[(c1*3+dt)*12 + c2] = pack(w2r,w2i)  for w2[(c2*12+c1)*3+dt]
__global__ void k_prep(const float* __restrict__ w1r, const float* __restrict__ w1i,
                       const float* __restrict__ w2r, const float* __restrict__ w2i,
                       unsigned int* __restrict__ wt1h, unsigned int* __restrict__ wt2h)
{
    int i = blockIdx.x * 256 + threadIdx.x;
    auto pk = [](float a, float b) {
        unsigned short ua = __half_as_ushort(__float2half_rn(a));
        unsigned short ub = __half_as_ushort(__float2half_rn(b));
        return (unsigned int)ua | ((unsigned int)ub << 16);
    };
    if (i < 300) {
        int c = i / 25, tap = i - c * 25;
        wt1h[tap*12 + c] = pk(w1r[i], w1i[i]);
    }
    if (i < 432) {
        int dt = i % 3; int t = i / 3; int c1 = t % 12; int c2 = t / 12;
        wt2h[(c1*3+dt)*12 + c2] = pk(w2r[i], w2i[i]);
    }
}

// ---------------- K1 (merged): z<NZ -> fused conv pipeline; z==NZ -> gram partials.
// Conv: conv1(1->12,5x5)+ReLU -> conv2(12->12,3t)+ReLU -> conv3(12->1) real
//       out = (x_re - dR*tsc)*pwv.  All MACs are v_pk_fma_f16 with SGPR weights,
//       packed-fp16 accumulators (error << tsc*pwv scale).
// launch_bounds(256,6): round-6 post-mortem — (256,8) forced VGPR=32 -> scratch
// spills (FETCH 124->429 MB). 6 waves/EU keeps ~40-48 VGPR, zero spill.
__global__ __launch_bounds__(256, 6) void k_work(
    const float* __restrict__ re, const float* __restrict__ im,
    const unsigned int* __restrict__ wt1h, const unsigned int* __restrict__ wt2h,
    const float* __restrict__ b1r, const float* __restrict__ b1i,
    const float* __restrict__ b2r, const float* __restrict__ b2i,
    const float* __restrict__ w3r, const float* __restrict__ w3i,
    const float* __restrict__ b3r,
    const float* __restrict__ tau_w, const float* __restrict__ p_w,
    const int* __restrict__ num_iter,
    float* __restrict__ out, float* __restrict__ gP)
{
    __shared__ unsigned int s_inv[2][12*36];   // double-buffered fp16 (re,im) input tile
    __shared__ float s_red[4][50];             // gram path only

    const int tid = threadIdx.x;

    if (blockIdx.z == NZ) {
        // ---------------- gram path ----------------
        const int gid = blockIdx.x + 14 * blockIdx.y;
        if (gid >= 80 * GSL) return;
        const int b = gid >> 3;              // 0..79 = chunk*16 + i*4 + j
        const int slice = gid & 7;
        const int chunk = b >> 4;
        const int pidx = b & 15;
        const int X0 = (pidx >> 2) * SXY;
        const int Y0 = (pidx & 3) * SXY;

        float acc[50];
        #pragma unroll
        for (int k = 0; k < 50; ++k) acc[k] = 0.f;

        const int npx = PXY * PXY;           // 13225
        for (int pi = slice*256 + tid; pi < npx; pi += 256*GSL) {
            int px = pi / PXY, py = pi % PXY;
            size_t base = (size_t)(X0 + px) * NXY + (Y0 + py);
            float xr[5], xi[5];
            #pragma unroll
            for (int r = 0; r < 5; ++r) {
                size_t a = (size_t)(chunk*5 + r) * NPIX + base;
                xr[r] = re[a]; xi[r] = im[a];
            }
            #pragma unroll
            for (int t1 = 0; t1 < 5; ++t1)
                #pragma unroll
                for (int t2 = 0; t2 < 5; ++t2) {
                    acc[(t1*5+t2)*2]   += xr[t1]*xr[t2] + xi[t1]*xi[t2];
                    acc[(t1*5+t2)*2+1] += xi[t1]*xr[t2] - xr[t1]*xi[t2];
                }
        }
        #pragma unroll
        for (int k = 0; k < 50; ++k) {
            float v = acc[k];
            for (int m = 32; m > 0; m >>= 1) v += __shfl_xor(v, m, 64);
            acc[k] = v;
        }
        int lane = tid & 63, wid = tid >> 6;
        if (lane == 0) {
            #pragma unroll
            for (int k = 0; k < 50; ++k) s_red[wid][k] = acc[k];
        }
        __syncthreads();
        if (tid < 50) {
            gP[(b*GSL + slice)*50 + tid] =
                s_red[0][tid] + s_red[1][tid] + s_red[2][tid] + s_red[3][tid];
        }
        return;
    }

    // ---------------- conv path ----------------
    const int tx = tid & 31;
    const int ty = tid >> 5;
    const int Y0 = blockIdx.x * TW;
    const int X0 = blockIdx.y * TH;
    const int z  = blockIdx.z;            // time chunk
    const int z0 = z * CH;                // first output frame of this chunk
    const int fs = (z == 0) ? 0 : z0 - 1; // first conv1 frame
    const int fe = (z0 + CH < NT) ? z0 + CH : NT - 1;  // last conv1 frame

    // wave-uniform params
    float rw3[12], iw3[12];
    unsigned int ub1[12], ub2[12];        // packed fp16 biases
    #pragma unroll
    for (int c = 0; c < 12; ++c) {
        ub1[c] = packh2f(b1r[c], b1i[c]);
        ub2[c] = packh2f(b2r[c], b2i[c]);
        rw3[c] = w3r[c]; iw3[c] = w3i[c];
    }
    const float b3v = b3r[0];
    const float tsc = fmaxf(tau_w[0], 0.f) / (float)num_iter[0];
    const float pwv = fmaxf(p_w[0], 0.f);

    // staging geometry (frame-independent): item0 = tid, item1 = tid+256 (if < 432)
    const int idx1 = tid + 256;
    int r0 = tid / 36, c0 = tid - r0*36;
    int gx0 = X0 + r0 - 2, gy0 = Y0 + c0 - 2;
    bool k0 = (gx0 >= 0) && (gx0 < NXY) && (gy0 >= 0) && (gy0 < NXY);
    const int a0 = (k0 ? gx0 : 0) * NXY + (k0 ? gy0 : 0);
    const float m0 = k0 ? 1.f : 0.f;
    int r1 = idx1 / 36, c1_ = idx1 - r1*36;
    int gx1 = X0 + r1 - 2, gy1 = Y0 + c1_ - 2;
    bool k1 = (gx1 >= 0) && (gx1 < NXY) && (gy1 >= 0) && (gy1 < NXY);
    const int a1 = (k1 ? gx1 : 0) * NXY + (k1 ? gy1 : 0);
    const float m1 = k1 ? 1.f : 0.f;

    // persistent h1 slots (relu'd fp16 pairs): hA=h[t-1], hB=h[t], hC=h[t+1]
    unsigned int hA[12], hB[12], hC[12];
    #pragma unroll
    for (int c = 0; c < 12; ++c) { hA[c] = 0u; hB[c] = 0u; hC[c] = 0u; }

    // conv1 for frame tf -> relu (packed) -> hs
    auto conv1_to = [&](int tf, unsigned int (&hs)[12]) {
        unsigned int a[12];
        #pragma unroll
        for (int c = 0; c < 12; ++c) a[c] = ub1[c];
        const unsigned int* sin_ = s_inv[tf & 1];
        #pragma unroll 1
        for (int ky = 0; ky < 5; ++ky) {
            const unsigned int* irow = &sin_[(ty+ky)*36 + tx];
            const unsigned int* wrow = &wt1h[ky*5*12];
            #pragma unroll
            for (int kx = 0; kx < 5; ++kx) {
                unsigned int x = irow[kx];
                const unsigned int* wp = wrow + kx*12;
                #pragma unroll
                for (int c = 0; c < 12; ++c) {
                    unsigned int w = wp[c];
                    CMACH(a[c], x, w);
                }
            }
        }
        #pragma unroll
        for (int c = 0; c < 12; ++c) { PKRELU(hs[c], a[c]); }
    };

    // conv2(+ReLU)+conv3+epilogue for output frame tc
    auto do_out = [&](int tc, unsigned int (&hp)[12], unsigned int (&hc)[12],
                      unsigned int (&hn)[12], bool hasP, bool hasN) {
        size_t idx = (size_t)tc*NPIX + (size_t)(X0+ty)*NXY + (Y0+tx);
        float reval = re[idx];             // issue early, hides under MACs
        unsigned int zz[12];
        #pragma unroll
        for (int c = 0; c < 12; ++c) zz[c] = ub2[c];
        if (hasP) {
            #pragma unroll
            for (int c1 = 0; c1 < 12; ++c1) {
                unsigned int x = hp[c1];
                const unsigned int* wp = &wt2h[(c1*3+0)*12];
                #pragma unroll
                for (int c2 = 0; c2 < 12; ++c2) {
                    unsigned int w = wp[c2];
                    CMACH(zz[c2], x, w);
                }
            }
        }
        {
            #pragma unroll
            for (int c1 = 0; c1 < 12; ++c1) {
                unsigned int x = hc[c1];
                const unsigned int* wp = &wt2h[(c1*3+1)*12];
                #pragma unroll
                for (int c2 = 0; c2 < 12; ++c2) {
                    unsigned int w = wp[c2];
                    CMACH(zz[c2], x, w);
                }
            }
        }
        if (hasN) {
            #pragma unroll
            for (int c1 = 0; c1 < 12; ++c1) {
                unsigned int x = hn[c1];
                const unsigned int* wp = &wt2h[(c1*3+2)*12];
                #pragma unroll
                for (int c2 = 0; c2 < 12; ++c2) {
                    unsigned int w = wp[c2];
                    CMACH(zz[c2], x, w);
                }
            }
        }
        float dR = b3v;
        #pragma unroll
        for (int c = 0; c < 12; ++c) {
            unsigned int zr;
            PKRELU(zr, zz[c]);
            __half2 hz = __builtin_bit_cast(__half2, zr);
            dR += __low2float(hz)*rw3[c] - __high2float(hz)*iw3[c];
        }
        out[idx] = (reval - dR * tsc) * pwv;
    };

    // prologue: stage frame fs
    {
        const float* rp = re + (size_t)fs * NPIX;
        const float* ip = im + (size_t)fs * NPIX;
        float pr0 = rp[a0], pi0 = ip[a0];
        float pr1 = 0.f, pi1 = 0.f;
        if (idx1 < 432) { pr1 = rp[a1]; pi1 = ip[a1]; }
        unsigned int* dst = s_inv[fs & 1];
        dst[tid] = packh2f(pr0*m0, pi0*m0);
        if (idx1 < 432) dst[idx1] = packh2f(pr1*m1, pi1*m1);
    }
    __syncthreads();

    #pragma unroll 1
    for (int f = fs; f <= fe; ++f) {
        // (1) issue next frame's loads early -> regs (latency hides under compute)
        float pr0 = 0.f, pi0 = 0.f, pr1 = 0.f, pi1 = 0.f;
        const bool more = (f < fe);
        if (more) {
            const float* rp = re + (size_t)(f+1) * NPIX;
            const float* ip = im + (size_t)(f+1) * NPIX;
            pr0 = rp[a0]; pi0 = ip[a0];
            if (idx1 < 432) { pr1 = rp[a1]; pi1 = ip[a1]; }
        }
        // (2) compute on already-staged frame f
        conv1_to(f, hC);
        const int tc = f - 1;
        if (f > fs && tc >= z0)
            do_out(tc, hA, hB, hC, tc >= 1, true);
        // (3) write prefetched regs to the other LDS buffer, then one barrier
        if (more) {
            unsigned int* dst = s_inv[(f+1) & 1];
            dst[tid] = packh2f(pr0*m0, pi0*m0);
            if (idx1 < 432) dst[idx1] = packh2f(pr1*m1, pi1*m1);
        }
        __syncthreads();
        #pragma unroll
        for (int c = 0; c < 12; ++c) { hA[c] = hB[c]; hB[c] = hC[c]; }
    }
    // final frame of the last chunk: tc = 24
    if (fe == NT - 1)
        do_out(NT - 1, hA, hB, hC, true, false);
}

// ---------------- K2: fold Gram partials -> Jacobi eig -> W (LDS) -> region-avg gA
__global__ __launch_bounds__(128) void k_post(
    const float* __restrict__ gP, const float* __restrict__ thres,
    float* __restrict__ gA)
{
    __shared__ float sW[80*50];
    const int tid = threadIdx.x;
    if (tid < 80) {
        const int b = tid;
        float Ar[5][5], Ai[5][5], Vr[5][5], Vi[5][5];
        #pragma unroll
        for (int a = 0; a < 5; ++a)
            #pragma unroll
            for (int c = 0; c < 5; ++c) {
                float sr = 0.f, si = 0.f;
                #pragma unroll
                for (int sl = 0; sl < GSL; ++sl) {
                    sr += gP[(b*GSL + sl)*50 + (a*5+c)*2];
                    si += gP[(b*GSL + sl)*50 + (a*5+c)*2 + 1];
                }
                Ar[a][c] = sr; Ai[a][c] = si;
                Vr[a][c] = (a==c) ? 1.f : 0.f;
                Vi[a][c] = 0.f;
            }
        for (int sw = 0; sw < 9; ++sw) {
            #pragma unroll
            for (int p = 0; p < 4; ++p) {
                #pragma unroll
                for (int q = p+1; q < 5; ++q) {
                    float apr = Ar[p][q], api = Ai[p][q];
                    float n2 = apr*apr + api*api;
                    if (n2 > 1e-24f) {
                        float mlen = sqrtf(n2);
                        float phr = apr / mlen, phi = api / mlen;
                        float tau = (Ar[q][q] - Ar[p][p]) / (2.f * mlen);
                        float tt = (tau >= 0.f ? 1.f : -1.f) / (fabsf(tau) + sqrtf(1.f + tau*tau));
                        float cc = 1.f / sqrtf(1.f + tt*tt);
                        float ss = tt * cc;
                        float wr2 = ss * phr, wi2 = ss * phi;
                        #pragma unroll
                        for (int k = 0; k < 5; ++k) {
                            float xr = Ar[k][p], xi2 = Ai[k][p];
                            float yr = Ar[k][q], yi = Ai[k][q];
                            Ar[k][p] = cc*xr - (wr2*yr + wi2*yi);
                            Ai[k][p] = cc*xi2 - (wr2*yi - wi2*yr);
                            Ar[k][q] = wr2*xr - wi2*xi2 + cc*yr;
                            Ai[k][q] = wr2*xi2 + wi2*xr + cc*yi;
                            float vxr = Vr[k][p], vxi = Vi[k][p];
                            float vyr = Vr[k][q], vyi = Vi[k][q];
                            Vr[k][p] = cc*vxr - (wr2*vyr + wi2*vyi);
                            Vi[k][p] = cc*vxi - (wr2*vyi - wi2*vyr);
                            Vr[k][q] = wr2*vxr - wi2*vxi + cc*vyr;
                            Vi[k][q] = wr2*vxi + wi2*vxr + cc*vyi;
                        }
                        #pragma unroll
                        for (int k = 0; k < 5; ++k) {
                            float xr = Ar[p][k], xi2 = Ai[p][k];
                            float yr = Ar[q][k], yi = Ai[q][k];
                            Ar[p][k] = cc*xr - (wr2*yr - wi2*yi);
                            Ai[p][k] = cc*xi2 - (wr2*yi + wi2*yr);
                            Ar[q][k] = wr2*xr + wi2*xi2 + cc*yr;
                            Ai[q][k] = wr2*xi2 - wi2*xr + cc*yi;
                        }
                    }
                }
            }
        }
        float sv[5], s0 = 0.f;
        #pragma unroll
        for (int k = 0; k < 5; ++k) { sv[k] = sqrtf(fmaxf(Ar[k][k], 0.f)); s0 = fmaxf(s0, sv[k]); }
        float th = fmaxf(thres[b], 0.f) * s0;
        float ratio[5];
        #pragma unroll
        for (int k = 0; k < 5; ++k)
            ratio[k] = sv[k] > 0.f ? fmaxf(sv[k] - th, 0.f) / sv[k] : 0.f;
        #pragma unroll
        for (int a = 0; a < 5; ++a)
            #pragma unroll
            for (int c = 0; c < 5; ++c) {
                float wr = 0.f, wi = 0.f;
                #pragma unroll
                for (int k = 0; k < 5; ++k) {
                    wr += ratio[k] * (Vr[a][k]*Vr[c][k] + Vi[a][k]*Vi[c][k]);
                    wi += ratio[k] * (Vi[a][k]*Vr[c][k] - Vr[a][k]*Vi[c][k]);
                }
                sW[b*50 + (a*5+c)*2]   = wr;
                sW[b*50 + (a*5+c)*2+1] = wi;
            }
    }
    __syncthreads();
    for (int it = tid; it < 245*25; it += 128) {
        int blk = it / 25, e = it % 25;
        int chunk = blk / 49;
        int rem = blk % 49;
        int rx = rem / 7, ry = rem % 7;
        int i0 = rx >> 1, i1 = (rx + 1) >> 1;
        int j0 = ry >> 1, j1 = (ry + 1) >> 1;
        float sr = 0.f, si = 0.f; int cnt = 0;
        for (int i = i0; i <= i1; ++i)
            for (int j = j0; j <= j1; ++j) {
                int b = chunk*16 + i*4 + j;
                sr += sW[b*50 + e*2];
                si += sW[b*50 + e*2 + 1];
                ++cnt;
            }
        float inv = 1.f / (float)cnt;
        gA[blk*50 + e*2]   = sr * inv;
        gA[blk*50 + e*2+1] = si * inv;
    }
}

// ---------------- K4: q_re = Re(Wavg * x5) ; out += q_re*(1-p_w)   (fp32 RMW)
__global__ __launch_bounds__(256) void k_final(
    const float* __restrict__ re, const float* __restrict__ im,
    const float* __restrict__ gA, const float* __restrict__ p_w,
    float* __restrict__ out)
{
    int pix = blockIdx.x * 256 + threadIdx.x;
    int chunk = blockIdx.y;
    int X = pix / NXY, Y = pix % NXY;
    int i_lo = (X - 4) / SXY; if (i_lo < 0) i_lo = 0;
    int i_hi = X / SXY;       if (i_hi > 3) i_hi = 3;
    int j_lo = (Y - 4) / SXY; if (j_lo < 0) j_lo = 0;
    int j_hi = Y / SXY;       if (j_hi > 3) j_hi = 3;
    int rx = i_lo + i_hi, ry = j_lo + j_hi;
    const float* wa = gA + (size_t)(chunk*49 + rx*7 + ry) * 50;
    float Wr[5][5], Wi[5][5];
    #pragma unroll
    for (int a = 0; a < 5; ++a)
        #pragma unroll
        for (int r = 0; r < 5; ++r) {
            Wr[a][r] = wa[(a*5+r)*2];
            Wi[a][r] = wa[(a*5+r)*2+1];
        }
    float xr[5], xi[5];
    #pragma unroll
    for (int r = 0; r < 5; ++r) {
        size_t a = (size_t)(chunk*5+r)*NPIX + pix;
        xr[r] = re[a]; xi[r] = im[a];
    }
    float qwv = 1.f - p_w[0];
    #pragma unroll
    for (int tl = 0; tl < 5; ++tl) {
        float qr = 0.f;
        #pragma unroll
        for (int r = 0; r < 5; ++r)
            qr += Wr[tl][r]*xr[r] - Wi[tl][r]*xi[r];
        size_t idx = (size_t)(chunk*5+tl)*NPIX + pix;
        out[idx] += qr*qwv;
    }
}

extern "C" void kernel_launch(void* const* d_in, const int* in_sizes, int n_in,
                              void* d_out, int out_size, void* d_ws, size_t ws_size,
                              hipStream_t stream)
{
    const float* re    = (const float*)d_in[0];
    const float* im    = (const float*)d_in[1];
    const float* w1r   = (const float*)d_in[2];
    const float* w1i   = (const float*)d_in[3];
    const float* b1r   = (const float*)d_in[4];
    const float* b1i   = (const float*)d_in[5];
    const float* b2r   = (const float*)d_in[8];
    const float* b2i   = (const float*)d_in[9];
    const float* w2r   = (const float*)d_in[6];
    const float* w2i   = (const float*)d_in[7];
    const float* w3r   = (const float*)d_in[10];
    const float* w3i   = (const float*)d_in[11];
    const float* b3r   = (const float*)d_in[12];
    const float* thres = (const float*)d_in[14];
    const float* tau_w = (const float*)d_in[15];
    const float* p_w   = (const float*)d_in[16];
    const int* num_iter= (const int*)d_in[17];

    float* ws = (float*)d_ws;
    unsigned int* wt1h = (unsigned int*)ws;          // 300 uints
    unsigned int* wt2h = wt1h + 512;                 // 432 uints (padded)
    float* gP  = (float*)(wt2h + 512);               // 80*GSL*50 = 32000 floats
    float* gA  = gP + 80*GSL*50;                     // 245*50 floats

    float* outf = (float*)d_out;

    k_prep<<<2, 256, 0, stream>>>(w1r, w1i, w2r, w2i, wt1h, wt2h);
    dim3 g1(NXY/TW, NXY/TH, NZ + 1);                 // z==NZ slice = gram blocks
    k_work<<<g1, 256, 0, stream>>>(re, im, wt1h, wt2h,
                                   b1r, b1i, b2r, b2i, w3r, w3i, b3r,
                                   tau_w, p_w, num_iter, outf, gP);
    k_post<<<1, 128, 0, stream>>>(gP, thres, gA);
    dim3 g4(NPIX/256, 5);
    k_final<<<g4, 256, 0, stream>>>(re, im, gA, p_w, outf);
}